// Round 4
// baseline (298.216 us; speedup 1.0000x reference)
//
#include <hip/hip_runtime.h>
#include <hip/hip_bf16.h>
#include <stdint.h>

typedef float f32x4 __attribute__((ext_vector_type(4)));
typedef short s16x8 __attribute__((ext_vector_type(8)));
typedef unsigned int u32x2 __attribute__((ext_vector_type(2)));
typedef unsigned int u32x4 __attribute__((ext_vector_type(4)));

#define MDIM 8192
#define NDIM 4096
#define KDIM 4096
#define NKT  64   // K-tiles of 64

__device__ __forceinline__ unsigned pkbf(float lo, float hi) {
  unsigned short l = __builtin_bit_cast(unsigned short, __float2bfloat16(lo));
  unsigned short h = __builtin_bit_cast(unsigned short, __float2bfloat16(hi));
  return ((unsigned)h << 16) | (unsigned)l;
}

__device__ __forceinline__ void gload16(const void* g, void* l) {
  __builtin_amdgcn_global_load_lds((const __attribute__((address_space(1))) int*)g,
                                   (__attribute__((address_space(3))) int*)l, 16, 0, 0);
}

// Convert f32 row-major [rows][4096] -> bf16 MFMA-fragment-subtiled layout.
// Per (row-tile rt of 256, K-tile kt of 64): 32 KB block =
//   [h:2 k-halves][f:16 row-frags][q:4 k-quads][fr:16 rows][e:8 bf16]
// Fragment slot = lane*16B: ds_read_b128 conflict-free, global_load_lds linear.
__global__ __launch_bounds__(256) void conv_tile(
    const float* __restrict__ X, const float* __restrict__ W,
    s16x8* __restrict__ wsA, s16x8* __restrict__ wsB) {
  __shared__ char lds[32768];
  const int b = blockIdx.x;
  const int tid = threadIdx.x;
  const float* src;
  s16x8* dst;
  int bi;
  if (b < 32 * NKT) { src = X; dst = wsA; bi = b; }
  else              { src = W; dst = wsB; bi = b - 32 * NKT; }
  const int rt = bi >> 6;
  const int kt = bi & 63;
  const int fr = tid >> 4;        // row within fragment
  const int c4 = (tid & 15) * 4;  // col (f32 units) within K-tile
  const int h = c4 >> 5, q = (c4 >> 3) & 3, eh = (c4 >> 2) & 1;
  #pragma unroll
  for (int f = 0; f < 16; ++f) {
    const int row = f * 16 + fr;
    f32x4 v = *(const f32x4*)(src + ((size_t)rt * 256 + row) * KDIM + kt * 64 + c4);
    u32x2 p = { pkbf(v[0], v[1]), pkbf(v[2], v[3]) };
    *(u32x2*)(lds + (h * 16 + f) * 1024 + (q * 16 + fr) * 16 + eh * 8) = p;
  }
  __syncthreads();
  const size_t ob = (size_t)bi * 2048;
  #pragma unroll
  for (int i = 0; i < 8; ++i)
    dst[ob + i * 256 + tid] = *(const s16x8*)(lds + (i * 256 + tid) * 16);
}

// 256x256x4096 bf16 GEMM, 8-phase balanced schedule, fused group epilogue.
__global__ __launch_bounds__(512, 2) void gemm256(
    const s16x8* __restrict__ wsA, const s16x8* __restrict__ wsB,
    const float* __restrict__ bias, const float* __restrict__ Wg,
    const float* __restrict__ bg, float* __restrict__ out) {
  extern __shared__ char smem[];
  const int tid = threadIdx.x;
  const int lane = tid & 63;
  const int wid = tid >> 6;      // 0..7
  const int wr = wid >> 2;       // 0..1  (wave row: 128 rows)
  const int wc = wid & 3;        // 0..3  (wave col: 64 cols)
  const int fr = lane & 15;
  const int q4 = lane >> 4;

  const int bid = blockIdx.x;
  const int swz = (bid & 7) * 64 + (bid >> 3);   // XCD-bijective (512 % 8 == 0)
  const int bm = swz >> 4;       // 0..31
  const int bn = swz & 15;       // 0..15

  const size_t aBase = (size_t)bm * NKT * 2048;  // 16B-slot units
  const size_t bBase = (size_t)bn * NKT * 2048;

  auto stage = [&](int kt, int db, int isB, int h) {
    const s16x8* s = (isB ? wsB + bBase : wsA + aBase)
                     + (size_t)kt * 2048 + h * 1024 + wid * 128 + lane;
    char* d = smem + isB * 65536 + db * 32768 + h * 16384 + wid * 2048;
    gload16(s, d);
    gload16(s + 64, d + 1024);
  };

  const char* aRd = smem + wr * 8192 + lane * 16;
  const char* bRd = smem + 65536 + wc * 4096 + lane * 16;

  f32x4 acc[8][4];
  #pragma unroll
  for (int m = 0; m < 8; ++m)
    #pragma unroll
    for (int n = 0; n < 4; ++n) acc[m][n] = (f32x4)0.0f;

  s16x8 af[4], bfr[4];

  // Per phase: 4m x 4n MFMAs. MH0 reads 4 A-frags + 4 B-frags, MH1 reads 4 A
  // (bfr persists across the MH0/MH1 pair). Stage schedule verified: every
  // target's last reader closes strictly before its staging phase; landings
  // covered by vmcnt(6)@P4/P8 (3 stages = 6 loads max in flight).
#define PHASE(DB, H, MH, SKT, SDB, SOP, SH, DOVM)                              \
  {                                                                            \
    stage(SKT, SDB, SOP, SH);                                                  \
    if ((MH) == 0) {                                                           \
      _Pragma("unroll")                                                        \
      for (int n = 0; n < 4; ++n)                                              \
        bfr[n] = *(const s16x8*)(bRd + (DB)*32768 + (H)*16384 + n * 1024);     \
    }                                                                          \
    _Pragma("unroll")                                                          \
    for (int m = 0; m < 4; ++m)                                                \
      af[m] = *(const s16x8*)(aRd + (DB)*32768 + (H)*16384 + ((MH)*4 + m) * 1024); \
    if (DOVM) asm volatile("s_waitcnt vmcnt(6)" ::: "memory");                 \
    __builtin_amdgcn_s_barrier();                                              \
    asm volatile("s_waitcnt lgkmcnt(0)" ::: "memory");                         \
    __builtin_amdgcn_s_setprio(1);                                             \
    _Pragma("unroll")                                                          \
    for (int m = 0; m < 4; ++m) {                                              \
      _Pragma("unroll")                                                        \
      for (int n = 0; n < 4; ++n)                                              \
        acc[(MH)*4 + m][n] = __builtin_amdgcn_mfma_f32_16x16x32_bf16(          \
            af[m], bfr[n], acc[(MH)*4 + m][n], 0, 0, 0);                       \
    }                                                                          \
    __builtin_amdgcn_s_setprio(0);                                             \
    __builtin_amdgcn_s_barrier();                                              \
  }

  // Prologue: t0 complete + t1.{Ak0,Bk0,Bk1}; t1.Ak1 staged at first P1.
  // vmcnt(3) guarantees s1..s5 landed (s6.l2, s7 drain under P1-P4's vmcnt(6)).
  stage(0, 0, 0, 0); stage(0, 0, 1, 0); stage(0, 0, 0, 1); stage(0, 0, 1, 1);
  stage(1, 1, 0, 0); stage(1, 1, 1, 0); stage(1, 1, 1, 1);
  asm volatile("s_waitcnt vmcnt(3)" ::: "memory");
  __builtin_amdgcn_s_barrier();

  for (int it = 0; it < 32; ++it) {
    const int u0 = 2 * it;
    const int k1 = u0 + 1;
    const int k2 = (u0 + 2 < NKT) ? u0 + 2 : NKT - 1;
    const int k3 = (u0 + 3 < NKT) ? u0 + 3 : NKT - 1;
    PHASE(0, 0, 0, k1, 1, 0, 1, 0)   // stage (u0+1).Ak1 -> db1.A.h1
    PHASE(0, 0, 1, k2, 0, 1, 0, 0)   // (u0+2).Bk0 -> db0.B.h0
    PHASE(0, 1, 0, k2, 0, 0, 0, 0)   // (u0+2).Ak0 -> db0.A.h0
    PHASE(0, 1, 1, k2, 0, 1, 1, 1)   // (u0+2).Bk1 -> db0.B.h1, vmcnt(6)
    PHASE(1, 0, 0, k2, 0, 0, 1, 0)   // (u0+2).Ak1 -> db0.A.h1
    PHASE(1, 0, 1, k3, 1, 1, 0, 0)   // (u0+3).Bk0 -> db1.B.h0
    PHASE(1, 1, 0, k3, 1, 0, 0, 0)   // (u0+3).Ak0 -> db1.A.h0
    PHASE(1, 1, 1, k3, 1, 1, 1, 1)   // (u0+3).Bk1 -> db1.B.h1, vmcnt(6)
  }
#undef PHASE

  // ---- drain, then fused group-linear epilogue ----
  asm volatile("s_waitcnt vmcnt(0)" ::: "memory");
  __builtin_amdgcn_s_barrier();

  float bv[4];
  #pragma unroll
  for (int n = 0; n < 4; ++n) bv[n] = bias[bn * 256 + wc * 64 + n * 16 + fr];

  // y = acc + bias -> bf16 into sY [Mf:16][Kh:8][1KB], diagonal order:
  // r = (j+q4)&3 spreads the 8 written slots across 8 distinct bank groups.
  #pragma unroll
  for (int m = 0; m < 8; ++m) {
    const int Mf = wr * 8 + m;
    #pragma unroll
    for (int np = 0; np < 2; ++np) {
      const int Kh = wc * 2 + np;
      #pragma unroll
      for (int j = 0; j < 8; ++j) {
        const int nn = np * 2 + (j >> 2);
        const int r = (j + q4) & 3;
        const int qq = (j >> 2) * 2 + (fr >> 3);
        const int frs = q4 * 4 + r;
        const float y = acc[m][nn][r] + bv[nn];
        *(unsigned short*)(smem + (Mf * 8 + Kh) * 1024 + (qq * 16 + frs) * 16 + (fr & 7) * 2)
            = __builtin_bit_cast(unsigned short, __float2bfloat16(y));
      }
    }
  }
  asm volatile("s_waitcnt lgkmcnt(0)" ::: "memory");
  __builtin_amdgcn_s_barrier();

  // out_g = sY_g @ Wg[g]^T + bg ; wave (wr,wc) keeps its 128x64 sub-tile,
  // K = its group's 128 y-cols (Kh = (wc>>1)*4 + s). Wg read direct from
  // global (L2-resident, converted in-reg) — proven path.
  const int g = bn * 2 + (wc >> 1);
  const float* wgb = Wg + (size_t)g * 16384;
  f32x4 acc2[8][4];
  #pragma unroll
  for (int m = 0; m < 8; ++m)
    #pragma unroll
    for (int n = 0; n < 4; ++n) acc2[m][n] = (f32x4)0.0f;

  #pragma unroll
  for (int s = 0; s < 4; ++s) {
    const int Kh = (wc >> 1) * 4 + s;
    s16x8 af2[8];
    #pragma unroll
    for (int m = 0; m < 8; ++m)
      af2[m] = *(const s16x8*)(smem + ((wr * 8 + m) * 8 + Kh) * 1024 + lane * 16);
    #pragma unroll
    for (int n = 0; n < 4; ++n) {
      const int ocl = (wc & 1) * 64 + n * 16 + fr;   // out col within group
      const float* wp = wgb + ocl * 128 + s * 32 + q4 * 8;
      f32x4 w0 = *(const f32x4*)wp;
      f32x4 w1 = *(const f32x4*)(wp + 4);
      u32x4 pw = { pkbf(w0[0], w0[1]), pkbf(w0[2], w0[3]),
                   pkbf(w1[0], w1[1]), pkbf(w1[2], w1[3]) };
      const s16x8 bfw = __builtin_bit_cast(s16x8, pw);
      #pragma unroll
      for (int m = 0; m < 8; ++m)
        acc2[m][n] = __builtin_amdgcn_mfma_f32_16x16x32_bf16(af2[m], bfw, acc2[m][n], 0, 0, 0);
    }
  }

  float bgv[4];
  #pragma unroll
  for (int n = 0; n < 4; ++n) bgv[n] = bg[bn * 256 + wc * 64 + n * 16 + fr];

  #pragma unroll
  for (int m = 0; m < 8; ++m) {
    #pragma unroll
    for (int n = 0; n < 4; ++n) {
      const int col = bn * 256 + wc * 64 + n * 16 + fr;
      #pragma unroll
      for (int r = 0; r < 4; ++r) {
        const size_t row = (size_t)bm * 256 + wr * 128 + m * 16 + q4 * 4 + r;
        out[row * NDIM + col] = acc2[m][n][r] + bgv[n];
      }
    }
  }
}

extern "C" void kernel_launch(void* const* d_in, const int* in_sizes, int n_in,
                              void* d_out, int out_size, void* d_ws, size_t ws_size,
                              hipStream_t stream) {
  const float* X    = (const float*)d_in[0];
  const float* W    = (const float*)d_in[1];
  const float* bias = (const float*)d_in[2];
  const float* Wg   = (const float*)d_in[3];
  const float* bg   = (const float*)d_in[4];
  float* out = (float*)d_out;

  s16x8* wsA = (s16x8*)d_ws;                       // 64 MB
  s16x8* wsB = wsA + ((size_t)MDIM * KDIM / 8);    // 32 MB

  hipFuncSetAttribute(reinterpret_cast<const void*>(gemm256),
                      hipFuncAttributeMaxDynamicSharedMemorySize, 131072);

  conv_tile<<<dim3(3072), dim3(256), 0, stream>>>(X, W, wsA, wsB);
  gemm256<<<dim3(512), dim3(512), 131072, stream>>>(wsA, wsB, bias, Wg, bg, out);
}